// Round 2
// baseline (78.918 us; speedup 1.0000x reference)
//
#include <hip/hip_runtime.h>

// Problem constants (match reference)
#define TI 256   // i-values per block (one per thread)
#define TJ 256   // j-values staged in LDS per block

__device__ __forceinline__ float fpow_pos(float x, float p) {
    // x >= 0; pow via hardware log2/exp2. x==0 -> log2=-inf -> exp2(-inf)=0. Correct for p>0.
    return __builtin_exp2f(p * __builtin_log2f(x));
}

__global__ __launch_bounds__(256) void gwave_forces(
    const float* __restrict__ ell,
    const float* __restrict__ theta,
    const float* __restrict__ fs,
    const float* __restrict__ mass,
    const unsigned char* __restrict__ frozen,   // numpy bool (all false in this test)
    const int* __restrict__ gsize_p,
    float* __restrict__ out,                    // [2*n]: out[i]=F_ell, out[n+i]=F_theta
    int n)
{
    const float PHI      = 1.61803398875f;
    const float INV_PHI  = 0.61803398875f;
    const float ONE_P_PHI= 2.61803398875f;
    const float TAU      = 6.2831855f;    // float32(2*pi)
    const float PI_F     = 3.14159274f;   // float32(pi)
    const float EPS      = 1e-10f;

    const int gs = *gsize_p;
    const float cw_ell = 2.0f / (float)gs;   // ELL_MAX / grid
    const float cw_th  = TAU  / (float)gs;

    __shared__ float s_ell[TJ];
    __shared__ float s_th[TJ];
    __shared__ float s_fs[TJ];
    __shared__ int   s_cell[TJ];   // ce*1024 + ct, or -1 if inactive/out-of-range

    const int tid = threadIdx.x;
    const int j0 = blockIdx.x * TJ;
    const int i  = blockIdx.y * TI + tid;

    // Stage j-chunk into LDS
    {
        int j = j0 + tid;
        if (j < n) {
            float e = ell[j];
            float t = theta[j];
            int ce = (int)floorf(e / cw_ell);
            ce = min(max(ce, 0), gs - 1);
            float tw = t - floorf(t / TAU) * TAU;       // jnp.mod(theta, TAU)
            int ct = (int)floorf(tw / cw_th);
            ct = min(max(ct, 0), gs - 1);
            s_ell[tid] = e;
            s_th[tid]  = t;
            s_fs[tid]  = fs[j];
            s_cell[tid] = frozen[j] ? -1 : (ce * 1024 + ct);
        } else {
            s_cell[tid] = -1;
            s_ell[tid] = 0.f; s_th[tid] = 0.f; s_fs[tid] = 0.f;
        }
    }
    __syncthreads();

    if (i >= n) return;

    const float e_i = ell[i];
    const float t_i = theta[i];
    const float f_i = fs[i];
    const float m_i = mass[i];
    const bool act_i = (frozen[i] == 0);

    int ce_i = (int)floorf(e_i / cw_ell);
    ce_i = min(max(ce_i, 0), gs - 1);
    float tw_i = t_i - floorf(t_i / TAU) * TAU;
    int ct_i = (int)floorf(tw_i / cw_th);
    ct_i = min(max(ct_i, 0), gs - 1);

    float Fe = 0.f, Ft = 0.f;

    if (act_i) {
        #pragma unroll 4
        for (int jj = 0; jj < TJ; ++jj) {
            int c = s_cell[jj];                 // LDS broadcast (all lanes same addr)
            // cell check (cheap)
            int ce_j = c >> 10;
            int ct_j = c & 1023;
            int dce = abs(ce_j - ce_i);
            int dct = abs(ct_j - ct_i);
            dct = min(dct, gs - dct);
            int j = j0 + jj;
            bool hit = (c >= 0) & (dce <= 1) & (dct <= 1) & (j != i);
            if (hit) {
                float dl  = s_ell[jj] - e_i;
                float dtr = s_th[jj]  - t_i + PI_F;
                // jnp.mod(x, 2pi): floor-mod, result in [0, 2pi)
                float r = fmodf(dtr, TAU);
                if (r < 0.f) r += TAU;
                float dt = r - PI_F;

                float adl = fabsf(dl);
                float adt = fabsf(dt);
                float inner = fpow_pos(adl, PHI) + fpow_pos(adt, PHI);
                float dL = fpow_pos(inner, INV_PHI) + EPS;
                float denom = fpow_pos(dL, ONE_P_PHI) * m_i + EPS;
                float fm = f_i * s_fs[jj] / denom;
                float inv_dL = 1.0f / dL;
                Fe += fm * dl * inv_dL;
                Ft += fm * dt * inv_dL;
            }
        }
    }

    // 16 partial contributions per output element -> atomic accumulate
    atomicAdd(&out[i], Fe);
    atomicAdd(&out[n + i], Ft);
}

extern "C" void kernel_launch(void* const* d_in, const int* in_sizes, int n_in,
                              void* d_out, int out_size, void* d_ws, size_t ws_size,
                              hipStream_t stream) {
    const float* ell   = (const float*)d_in[0];
    const float* theta = (const float*)d_in[1];
    const float* fs    = (const float*)d_in[2];
    const float* mass  = (const float*)d_in[3];
    const unsigned char* frozen = (const unsigned char*)d_in[4];
    const int* gsize   = (const int*)d_in[5];
    float* out = (float*)d_out;
    const int n = in_sizes[0];

    // d_out is poisoned once (0xAA) before timing and never re-poisoned:
    // zero it every call before accumulation.
    (void)hipMemsetAsync(out, 0, (size_t)out_size * sizeof(float), stream);

    dim3 block(256);
    dim3 grid((n + TJ - 1) / TJ, (n + TI - 1) / TI);
    gwave_forces<<<grid, block, 0, stream>>>(ell, theta, fs, mass, frozen, gsize, out, n);
}

// Round 3
// 31.498 us; speedup vs baseline: 2.5055x; 2.5055x over previous
//
#include <hip/hip_runtime.h>

#define TPB_SORT 1024
#define MAXC 1024   // max grid cells held in LDS (supports gs <= 32; test uses gs=32)

__device__ __forceinline__ float fpow_pos(float x, float p) {
    // x >= 0; pow via hardware log2/exp2. x==0 -> log2=-inf -> exp2(-inf)=0 (p>0).
    return __builtin_exp2f(p * __builtin_log2f(x));
}

__device__ __forceinline__ int cell_of(float e, float t, int gs,
                                       float cw_ell, float cw_th, float TAU) {
    int ce = (int)floorf(e / cw_ell);
    ce = min(max(ce, 0), gs - 1);
    float tw = t - floorf(t / TAU) * TAU;   // jnp.mod(theta, TAU), floor-mod
    int ct = (int)floorf(tw / cw_th);
    ct = min(max(ct, 0), gs - 1);
    return ce * gs + ct;
}

// Kernel 1 (single block): zero out[], counting-sort tokens by cell into ws.
__global__ __launch_bounds__(TPB_SORT) void build_cells(
    const float* __restrict__ ell, const float* __restrict__ theta,
    const float* __restrict__ fs, const unsigned char* __restrict__ frozen,
    const int* __restrict__ gsize_p, int n,
    int* __restrict__ g_start, float* __restrict__ g_sell,
    float* __restrict__ g_sth, float* __restrict__ g_sfs,
    int* __restrict__ g_sidx, float* __restrict__ out)
{
    __shared__ int s_cnt[MAXC];
    __shared__ int s_scan[MAXC];
    const int tid = threadIdx.x;
    const int gs = *gsize_p;
    const int C = gs * gs;                  // assumed <= MAXC
    const float TAU = 6.2831855f;           // float32(2*pi)
    const float cw_ell = 2.0f / (float)gs;
    const float cw_th  = TAU  / (float)gs;

    // zero the output accumulator (harness poisons once; we own re-zeroing)
    for (int r = tid; r < 2 * n; r += TPB_SORT) out[r] = 0.f;
    for (int c = tid; c < C; c += TPB_SORT) s_cnt[c] = 0;
    __syncthreads();

    // histogram (active tokens only)
    for (int r = tid; r < n; r += TPB_SORT) {
        if (frozen[r]) continue;
        int c = cell_of(ell[r], theta[r], gs, cw_ell, cw_th, TAU);
        atomicAdd(&s_cnt[c], 1);
    }
    __syncthreads();

    // inclusive Hillis-Steele scan over C (<= TPB_SORT) entries
    int v = (tid < C) ? s_cnt[tid] : 0;
    s_scan[tid] = v;
    __syncthreads();
    for (int off = 1; off < C; off <<= 1) {
        int x = s_scan[tid];
        int y = (tid >= off) ? s_scan[tid - off] : 0;
        __syncthreads();
        s_scan[tid] = x + y;
        __syncthreads();
    }
    if (tid < C) {
        int excl = (tid > 0) ? s_scan[tid - 1] : 0;
        g_start[tid] = excl;
        s_cnt[tid] = excl;                  // reuse as scatter cursor
        if (tid == C - 1) g_start[C] = s_scan[C - 1];
    }
    __syncthreads();

    // scatter sorted token data
    for (int r = tid; r < n; r += TPB_SORT) {
        if (frozen[r]) continue;
        float e = ell[r], t = theta[r];
        int c = cell_of(e, t, gs, cw_ell, cw_th, TAU);
        int pos = atomicAdd(&s_cnt[c], 1);
        g_sell[pos] = e;
        g_sth[pos]  = t;
        g_sfs[pos]  = fs[r];
        g_sidx[pos] = r;
    }
}

// Kernel 2: one thread per (receiver i, one of its 9 neighbor cells).
__global__ __launch_bounds__(256) void gwave_forces(
    const float* __restrict__ ell, const float* __restrict__ theta,
    const float* __restrict__ fs, const float* __restrict__ mass,
    const unsigned char* __restrict__ frozen, const int* __restrict__ gsize_p,
    int n,
    const int* __restrict__ g_start, const float* __restrict__ g_sell,
    const float* __restrict__ g_sth, const float* __restrict__ g_sfs,
    const int* __restrict__ g_sidx, float* __restrict__ out)
{
    const float PHI       = 1.61803398875f;
    const float INV_PHI   = 0.61803398875f;
    const float ONE_P_PHI = 2.61803398875f;
    const float TAU  = 6.2831855f;          // float32(2*pi)
    const float PI_F = 3.14159274f;         // float32(pi)
    const float EPS  = 1e-10f;

    int linear = blockIdx.x * 256 + threadIdx.x;
    int i = linear / 9;
    int k = linear - i * 9;
    if (i >= n) return;
    if (frozen[i]) return;

    const int gs = *gsize_p;
    const float cw_ell = 2.0f / (float)gs;
    const float cw_th  = TAU  / (float)gs;

    float e_i = ell[i], t_i = theta[i];
    int ce_i = min(max((int)floorf(e_i / cw_ell), 0), gs - 1);
    float tw = t_i - floorf(t_i / TAU) * TAU;
    int ct_i = min(max((int)floorf(tw / cw_th), 0), gs - 1);

    // ell cells do NOT wrap (|ce_j - ce_i| <= 1); theta cells wrap (gs >= 4 assumed)
    int ce = ce_i + (k / 3) - 1;
    if (ce < 0 || ce >= gs) return;
    int ct = ct_i + (k % 3) - 1;
    if (ct < 0) ct += gs; else if (ct >= gs) ct -= gs;
    int c = ce * gs + ct;

    int p0 = g_start[c], p1 = g_start[c + 1];
    float f_i = fs[i], m_i = mass[i];
    float Fe = 0.f, Ft = 0.f;

    for (int p = p0; p < p1; ++p) {
        if (g_sidx[p] == i) continue;       // exclude self
        float dl  = g_sell[p] - e_i;
        float dtr = g_sth[p]  - t_i + PI_F;
        float r = fmodf(dtr, TAU);          // -> floor-mod
        if (r < 0.f) r += TAU;
        float dt = r - PI_F;

        float inner = fpow_pos(fabsf(dl), PHI) + fpow_pos(fabsf(dt), PHI);
        float dL = fpow_pos(inner, INV_PHI) + EPS;
        float denom = fpow_pos(dL, ONE_P_PHI) * m_i + EPS;
        float fm = f_i * g_sfs[p] / denom;
        float inv = 1.0f / dL;
        Fe += fm * dl * inv;
        Ft += fm * dt * inv;
    }

    atomicAdd(&out[i],     Fe);
    atomicAdd(&out[n + i], Ft);
}

extern "C" void kernel_launch(void* const* d_in, const int* in_sizes, int n_in,
                              void* d_out, int out_size, void* d_ws, size_t ws_size,
                              hipStream_t stream) {
    const float* ell   = (const float*)d_in[0];
    const float* theta = (const float*)d_in[1];
    const float* fs    = (const float*)d_in[2];
    const float* mass  = (const float*)d_in[3];
    const unsigned char* frozen = (const unsigned char*)d_in[4];
    const int* gsize   = (const int*)d_in[5];
    float* out = (float*)d_out;
    const int n = in_sizes[0];

    // workspace layout (floats/ints are 4B):
    // [0 .. 2047]        g_start (C+1 <= 1025 ints, padded)
    // [2048 .. 2048+4n)  sorted ell | theta | fs | idx
    int*   g_start = (int*)d_ws;
    float* g_sell  = (float*)d_ws + 2048;
    float* g_sth   = g_sell + n;
    float* g_sfs   = g_sth + n;
    int*   g_sidx  = (int*)(g_sfs + n);

    build_cells<<<1, TPB_SORT, 0, stream>>>(ell, theta, fs, frozen, gsize, n,
                                            g_start, g_sell, g_sth, g_sfs, g_sidx, out);

    int total = n * 9;
    gwave_forces<<<(total + 255) / 256, 256, 0, stream>>>(
        ell, theta, fs, mass, frozen, gsize, n,
        g_start, g_sell, g_sth, g_sfs, g_sidx, out);
}

// Round 4
// 21.513 us; speedup vs baseline: 3.6684x; 1.4641x over previous
//
#include <hip/hip_runtime.h>

#define TPB 1024
#define MAXC 1024   // supports gs <= 32 (test: gs = 32)

__device__ __forceinline__ float fpow_pos(float x, float p) {
    // x >= 0; pow via hardware log2/exp2. x==0 -> log2=-inf -> exp2(-inf)=0 (p>0).
    return __builtin_exp2f(p * __builtin_log2f(x));
}

// Kernel 1 (single block, 1024 thr): zero out[], counting-sort tokens by cell.
// Sorted record = float4(ell, theta, fs, meta) with meta = idx | ce<<22 | ct<<27.
__global__ __launch_bounds__(TPB) void build_cells(
    const float* __restrict__ ell, const float* __restrict__ theta,
    const float* __restrict__ fs, const unsigned char* __restrict__ frozen,
    const int* __restrict__ gsize_p, int n,
    int* __restrict__ g_start, float4* __restrict__ g_pack,
    float* __restrict__ out)
{
    __shared__ int s_cnt[MAXC];
    __shared__ int s_cur[MAXC];
    __shared__ int s_wsum[TPB / 64];

    const int tid  = threadIdx.x;
    const int lane = tid & 63;
    const int wid  = tid >> 6;
    const int gs = *gsize_p;
    const int C = gs * gs;                 // <= MAXC assumed
    const float TAU = 6.2831855f;          // float32(2*pi)
    const float cw_ell = 2.0f / (float)gs;
    const float cw_th  = TAU  / (float)gs;

    // zero output accumulator (harness poisons once; we own re-zeroing)
    {
        float4* o4 = (float4*)out;
        int m4 = (2 * n) >> 2;
        for (int r = tid; r < m4; r += TPB) o4[r] = make_float4(0.f, 0.f, 0.f, 0.f);
        for (int r = (m4 << 2) + tid; r < 2 * n; r += TPB) out[r] = 0.f;
    }
    for (int c = tid; c < C; c += TPB) s_cnt[c] = 0;
    __syncthreads();

    const float4* ell4 = (const float4*)ell;
    const float4* th4  = (const float4*)theta;
    const float4* fs4  = (const float4*)fs;
    const uchar4* fr4  = (const uchar4*)frozen;
    const int n4 = n >> 2;

    // ---- histogram (vectorized; full unroll keeps vector-elem indices static) ----
    for (int b = tid; b < n4; b += TPB) {
        float4 e4 = ell4[b]; float4 t4 = th4[b]; uchar4 f4 = fr4[b];
        #pragma unroll
        for (int m = 0; m < 4; ++m) {
            float e = m == 0 ? e4.x : m == 1 ? e4.y : m == 2 ? e4.z : e4.w;
            float t = m == 0 ? t4.x : m == 1 ? t4.y : m == 2 ? t4.z : t4.w;
            unsigned char fr = m == 0 ? f4.x : m == 1 ? f4.y : m == 2 ? f4.z : f4.w;
            if (!fr) {
                int ce = min(max((int)floorf(e / cw_ell), 0), gs - 1);
                float tw = t - floorf(t / TAU) * TAU;
                int ct = min(max((int)floorf(tw / cw_th), 0), gs - 1);
                atomicAdd(&s_cnt[ce * gs + ct], 1);
            }
        }
    }
    for (int r = (n4 << 2) + tid; r < n; r += TPB) {
        if (!frozen[r]) {
            float e = ell[r], t = theta[r];
            int ce = min(max((int)floorf(e / cw_ell), 0), gs - 1);
            float tw = t - floorf(t / TAU) * TAU;
            int ct = min(max((int)floorf(tw / cw_th), 0), gs - 1);
            atomicAdd(&s_cnt[ce * gs + ct], 1);
        }
    }
    __syncthreads();

    // ---- scan: wave-level shuffle scan + 16-wave second level (2 barriers) ----
    int cnt = (tid < C) ? s_cnt[tid] : 0;
    int v = cnt;
    #pragma unroll
    for (int d = 1; d < 64; d <<= 1) {
        int u = __shfl_up(v, d, 64);
        if (lane >= d) v += u;
    }
    if (lane == 63) s_wsum[wid] = v;
    __syncthreads();
    if (wid == 0) {
        int w = (lane < TPB / 64) ? s_wsum[lane] : 0;
        #pragma unroll
        for (int d = 1; d < TPB / 64; d <<= 1) {
            int u = __shfl_up(w, d, 64);
            if (lane >= d) w += u;
        }
        if (lane < TPB / 64) s_wsum[lane] = w;   // inclusive wave sums
    }
    __syncthreads();
    int incl = v + ((wid > 0) ? s_wsum[wid - 1] : 0);
    int excl = incl - cnt;
    if (tid < C) {
        g_start[tid] = excl;
        s_cur[tid] = excl;
        if (tid == C - 1) g_start[C] = incl;     // total active count M
    }
    __syncthreads();

    // ---- scatter (vectorized reload; meta packs idx + cell coords) ----
    for (int b = tid; b < n4; b += TPB) {
        float4 e4 = ell4[b]; float4 t4 = th4[b]; float4 s4 = fs4[b]; uchar4 f4 = fr4[b];
        #pragma unroll
        for (int m = 0; m < 4; ++m) {
            float e = m == 0 ? e4.x : m == 1 ? e4.y : m == 2 ? e4.z : e4.w;
            float t = m == 0 ? t4.x : m == 1 ? t4.y : m == 2 ? t4.z : t4.w;
            float f = m == 0 ? s4.x : m == 1 ? s4.y : m == 2 ? s4.z : s4.w;
            unsigned char fr = m == 0 ? f4.x : m == 1 ? f4.y : m == 2 ? f4.z : f4.w;
            if (!fr) {
                int r = (b << 2) + m;
                int ce = min(max((int)floorf(e / cw_ell), 0), gs - 1);
                float tw = t - floorf(t / TAU) * TAU;
                int ct = min(max((int)floorf(tw / cw_th), 0), gs - 1);
                int pos = atomicAdd(&s_cur[ce * gs + ct], 1);
                int meta = r | (ce << 22) | (ct << 27);
                g_pack[pos] = make_float4(e, t, f, __int_as_float(meta));
            }
        }
    }
    for (int r = (n4 << 2) + tid; r < n; r += TPB) {
        if (!frozen[r]) {
            float e = ell[r], t = theta[r];
            int ce = min(max((int)floorf(e / cw_ell), 0), gs - 1);
            float tw = t - floorf(t / TAU) * TAU;
            int ct = min(max((int)floorf(tw / cw_th), 0), gs - 1);
            int pos = atomicAdd(&s_cur[ce * gs + ct], 1);
            int meta = r | (ce << 22) | (ct << 27);
            g_pack[pos] = make_float4(e, t, fs[r], __int_as_float(meta));
        }
    }
}

// Kernel 2: one thread per (sorted receiver p, one of its 9 neighbor cells).
__global__ __launch_bounds__(256) void gwave_forces(
    const float* __restrict__ mass,
    const int* __restrict__ gsize_p, int n,
    const int* __restrict__ g_start, const float4* __restrict__ g_pack,
    float* __restrict__ out)
{
    const float PHI       = 1.61803398875f;
    const float INV_PHI   = 0.61803398875f;
    const float ONE_P_PHI = 2.61803398875f;
    const float TAU  = 6.2831855f;     // float32(2*pi)
    const float PI_F = 3.14159274f;    // float32(pi)
    const float EPS  = 1e-10f;

    const int gs = *gsize_p;
    const int C = gs * gs;
    const int t = blockIdx.x * 256 + threadIdx.x;
    const int p = t / 9;
    const int k = t - p * 9;
    const int M = g_start[C];          // active token count
    if (p >= M) return;

    float4 me = g_pack[p];
    const int meta = __float_as_int(me.w);
    const int idx  = meta & 0x3FFFFF;
    const int ce_i = (meta >> 22) & 31;
    const int ct_i = (meta >> 27) & 31;

    // ell cells don't wrap; theta cells wrap (gs >= 4 assumed; test gs = 32)
    int ce = ce_i + (k / 3) - 1;
    if (ce < 0 || ce >= gs) return;
    int ct = ct_i + (k % 3) - 1;
    if (ct < 0) ct += gs; else if (ct >= gs) ct -= gs;
    const int c = ce * gs + ct;

    const int p0 = g_start[c], p1 = g_start[c + 1];
    const float e_i = me.x, t_i = me.y, f_i = me.z;
    const float m_i = mass[idx];
    float Fe = 0.f, Ft = 0.f;

    for (int q = p0; q < p1; ++q) {
        if (q == p) continue;          // self (each token appears exactly once)
        float4 o = g_pack[q];
        float dl = o.x - e_i;
        // jnp.mod(dtheta + pi, tau) - pi; masked pairs are never near the 0/tau
        // rounding boundary (|dtheta| <= 2 cells), so predicated wrap == floor-mod.
        float x = o.y - t_i + PI_F;    // in (-pi, 3pi) for theta in [0, tau)
        x += (x < 0.f)   ? TAU : 0.f;
        x -= (x >= TAU)  ? TAU : 0.f;
        float dt = x - PI_F;

        float inner = fpow_pos(fabsf(dl), PHI) + fpow_pos(fabsf(dt), PHI);
        float dL = fpow_pos(inner, INV_PHI) + EPS;
        float denom = fpow_pos(dL, ONE_P_PHI) * m_i + EPS;
        float fm = f_i * o.z / denom;
        float inv = 1.0f / dL;
        Fe += fm * dl * inv;
        Ft += fm * dt * inv;
    }

    atomicAdd(&out[idx],     Fe);
    atomicAdd(&out[n + idx], Ft);
}

extern "C" void kernel_launch(void* const* d_in, const int* in_sizes, int n_in,
                              void* d_out, int out_size, void* d_ws, size_t ws_size,
                              hipStream_t stream) {
    const float* ell   = (const float*)d_in[0];
    const float* theta = (const float*)d_in[1];
    const float* fs    = (const float*)d_in[2];
    const float* mass  = (const float*)d_in[3];
    const unsigned char* frozen = (const unsigned char*)d_in[4];
    const int* gsize   = (const int*)d_in[5];
    float* out = (float*)d_out;
    const int n = in_sizes[0];

    // workspace: g_start = 1040 ints (4160 B, 16B-aligned end), then g_pack[n]
    int*    g_start = (int*)d_ws;
    float4* g_pack  = (float4*)((char*)d_ws + 4160);

    build_cells<<<1, TPB, 0, stream>>>(ell, theta, fs, frozen, gsize, n,
                                       g_start, g_pack, out);

    int total = n * 9;
    gwave_forces<<<(total + 255) / 256, 256, 0, stream>>>(
        mass, gsize, n, g_start, g_pack, out);
}